// Round 1
// baseline (113.668 us; speedup 1.0000x reference)
//
#include <hip/hip_runtime.h>

#define Bn 16
#define Qn 128
#define Kn 128
#define Dn 512
#define Hn 512
#define NEGV (-1e6f)

__device__ __forceinline__ float fast_tanh(float x) {
  float ax = __builtin_fabsf(x);
  float e  = __expf(-2.0f * ax);                       // v_exp_f32 path
  float r  = (1.0f - e) * __builtin_amdgcn_rcpf(1.0f + e);
  return __builtin_copysignf(r, x);
}

// ---------------- Kernel 1: projections (f32 tiled GEMM) ----------------
// Virtual C[4096][512]: rows 0..2047 = queries@Wq -> qp, rows 2048.. = keys@Wk -> kp
// 64x64 tile, BK=16, 256 threads, 4x4 per thread.
__global__ __launch_bounds__(256) void proj_kernel(
    const float* __restrict__ queries, const float* __restrict__ keys,
    const float* __restrict__ Wq, const float* __restrict__ Wk,
    float* __restrict__ qp, float* __restrict__ kp)
{
  __shared__ float AsT[16][68];   // [k][m], pad 68 (272B rows, 16B-aligned)
  __shared__ float Bs[16][64];    // [k][n]
  const int t  = threadIdx.x;
  const int tx = t & 15, ty = t >> 4;
  const int rowTile = blockIdx.x;   // 0..63
  const int colTile = blockIdx.y;   // 0..7
  const bool isQ = rowTile < 32;
  const float* A = isQ ? queries : keys;
  const float* W = isQ ? Wq : Wk;
  float* C       = isQ ? qp : kp;
  const int rowBase = (isQ ? rowTile : rowTile - 32) * 64;
  const int n0 = colTile * 64;

  float c[4][4];
  #pragma unroll
  for (int i = 0; i < 4; ++i)
    #pragma unroll
    for (int j = 0; j < 4; ++j) c[i][j] = 0.f;

  const int am  = t >> 2;         // 0..63  (A row within tile)
  const int akq = (t & 3) * 4;    // k sub-offset 0,4,8,12
  const int bkr = t >> 4;         // 0..15  (B k-row)
  const int bnq = (t & 15) * 4;   // B col offset

  for (int k0 = 0; k0 < Dn; k0 += 16) {
    float4 av = *(const float4*)(A + (size_t)(rowBase + am) * Dn + k0 + akq);
    float4 bv = *(const float4*)(W + (size_t)(k0 + bkr) * Hn + n0 + bnq);
    __syncthreads();              // previous iter done reading LDS
    AsT[akq + 0][am] = av.x;
    AsT[akq + 1][am] = av.y;
    AsT[akq + 2][am] = av.z;
    AsT[akq + 3][am] = av.w;
    *(float4*)&Bs[bkr][bnq] = bv;
    __syncthreads();
    #pragma unroll
    for (int kk = 0; kk < 16; ++kk) {
      float4 a4 = *(const float4*)&AsT[kk][ty * 4];
      float4 b4 = *(const float4*)&Bs[kk][tx * 4];
      float a[4] = {a4.x, a4.y, a4.z, a4.w};
      float b[4] = {b4.x, b4.y, b4.z, b4.w};
      #pragma unroll
      for (int i = 0; i < 4; ++i)
        #pragma unroll
        for (int j = 0; j < 4; ++j)
          c[i][j] = __builtin_fmaf(a[i], b[j], c[i][j]);
    }
  }
  #pragma unroll
  for (int i = 0; i < 4; ++i) {
    float4 o = {c[i][0], c[i][1], c[i][2], c[i][3]};
    *(float4*)(C + (size_t)(rowBase + ty * 4 + i) * Hn + n0 + tx * 4) = o;
  }
}

// ------------- Kernel 2: scores (tanh-reduce) + masked softmax -------------
// Block: (batch b, q-tile of 8). 256 threads. Each thread: 2q x 2k pairs,
// reduce over H in chunks of 64 staged in LDS.
__global__ __launch_bounds__(256) void score_softmax_kernel(
    const float* __restrict__ qp, const float* __restrict__ kp,
    const float* __restrict__ wv, const int* __restrict__ valid_lens,
    float* __restrict__ attn)
{
  __shared__ float KPl[128][65];
  __shared__ float QPl[8][65];
  __shared__ float WVl[512];
  __shared__ float S[8][132];
  const int t  = threadIdx.x;
  const int b  = blockIdx.y;
  const int q0 = blockIdx.x * 8;

  if (t < 128) {
    float4 w4 = *(const float4*)(wv + t * 4);
    *(float4*)&WVl[t * 4] = w4;
  }

  const int q2 = (t >> 6) * 2;    // 0,2,4,6 (per wave)
  const int k0 = (t & 63) * 2;    // 0..126
  float acc[2][2] = {{0.f, 0.f}, {0.f, 0.f}};

  const int qr  = t >> 4;         // for q staging (t<128): 0..7
  const int qc4 = t & 15;

  for (int c = 0; c < 8; ++c) {
    const int h0 = c * 64;
    float4 kreg[8];
    #pragma unroll
    for (int it = 0; it < 8; ++it) {
      int f  = t + 256 * it;
      int kr = f >> 4, c4 = f & 15;
      kreg[it] = *(const float4*)(kp + ((size_t)(b * Kn + kr)) * Hn + h0 + c4 * 4);
    }
    float4 qreg = {0.f, 0.f, 0.f, 0.f};
    if (t < 128)
      qreg = *(const float4*)(qp + ((size_t)(b * Qn + q0 + qr)) * Hn + h0 + qc4 * 4);
    __syncthreads();              // previous chunk done reading LDS
    #pragma unroll
    for (int it = 0; it < 8; ++it) {
      int f  = t + 256 * it;
      int kr = f >> 4, c4 = f & 15;
      KPl[kr][c4 * 4 + 0] = kreg[it].x;
      KPl[kr][c4 * 4 + 1] = kreg[it].y;
      KPl[kr][c4 * 4 + 2] = kreg[it].z;
      KPl[kr][c4 * 4 + 3] = kreg[it].w;
    }
    if (t < 128) {
      QPl[qr][qc4 * 4 + 0] = qreg.x;
      QPl[qr][qc4 * 4 + 1] = qreg.y;
      QPl[qr][qc4 * 4 + 2] = qreg.z;
      QPl[qr][qc4 * 4 + 3] = qreg.w;
    }
    __syncthreads();
    #pragma unroll 4
    for (int h = 0; h < 64; ++h) {
      float wvh = WVl[h0 + h];
      float qa  = QPl[q2][h];
      float qb  = QPl[q2 + 1][h];
      float kva = KPl[k0][h];
      float kvb = KPl[k0 + 1][h];
      acc[0][0] = __builtin_fmaf(wvh, fast_tanh(qa + kva), acc[0][0]);
      acc[0][1] = __builtin_fmaf(wvh, fast_tanh(qa + kvb), acc[0][1]);
      acc[1][0] = __builtin_fmaf(wvh, fast_tanh(qb + kva), acc[1][0]);
      acc[1][1] = __builtin_fmaf(wvh, fast_tanh(qb + kvb), acc[1][1]);
    }
  }

  __syncthreads();
  S[q2][k0]     = acc[0][0];
  S[q2][k0 + 1] = acc[0][1];
  S[q2 + 1][k0]     = acc[1][0];
  S[q2 + 1][k0 + 1] = acc[1][1];
  __syncthreads();

  // masked softmax: row r handled by 32 threads
  const int r    = t >> 5;
  const int lane = t & 31;
  const int vlen = valid_lens[b];
  float s[4];
  bool ok[4];
  float m = NEGV;
  #pragma unroll
  for (int j = 0; j < 4; ++j) {
    int col = lane + 32 * j;
    s[j]  = S[r][col];
    ok[j] = col < vlen;
    if (ok[j]) m = fmaxf(m, s[j]);
  }
  #pragma unroll
  for (int xm = 16; xm >= 1; xm >>= 1) m = fmaxf(m, __shfl_xor(m, xm));
  float e[4], sum = 0.f;
  #pragma unroll
  for (int j = 0; j < 4; ++j) {
    e[j] = ok[j] ? __expf(s[j] - m) : 0.f;
    sum += e[j];
  }
  #pragma unroll
  for (int xm = 16; xm >= 1; xm >>= 1) sum += __shfl_xor(sum, xm);
  float inv = 1.0f / sum;
  #pragma unroll
  for (int j = 0; j < 4; ++j)
    attn[((size_t)(b * Qn) + q0 + r) * Kn + lane + 32 * j] = e[j] * inv;
}

// ---------------- Kernel 3: out = attn @ values ----------------
// Block: (b, q-tile of 8). Wave w handles 2 q rows; lane covers 8 d-cols.
__global__ __launch_bounds__(256) void av_kernel(
    const float* __restrict__ attn, const float* __restrict__ values,
    float* __restrict__ out)
{
  __shared__ float Sl[8][128];
  const int t  = threadIdx.x;
  const int b  = blockIdx.y;
  const int q0 = blockIdx.x * 8;
  {
    int r = t >> 5, c4 = t & 31;
    float4 a4 = *(const float4*)(attn + ((size_t)(b * Qn) + q0 + r) * Kn + c4 * 4);
    *(float4*)&Sl[r][c4 * 4] = a4;
  }
  __syncthreads();
  const int w    = t >> 6;
  const int lane = t & 63;
  const int q2   = w * 2;
  const int d0   = lane * 8;
  float acc0[8] = {0.f, 0.f, 0.f, 0.f, 0.f, 0.f, 0.f, 0.f};
  float acc1[8] = {0.f, 0.f, 0.f, 0.f, 0.f, 0.f, 0.f, 0.f};
  #pragma unroll 2
  for (int k = 0; k < 128; ++k) {
    const float* vrow = values + ((size_t)(b * Kn + k)) * Dn + d0;
    float4 v0 = *(const float4*)(vrow);
    float4 v1 = *(const float4*)(vrow + 4);
    float a0 = Sl[q2][k];
    float a1 = Sl[q2 + 1][k];
    acc0[0] = __builtin_fmaf(a0, v0.x, acc0[0]);
    acc0[1] = __builtin_fmaf(a0, v0.y, acc0[1]);
    acc0[2] = __builtin_fmaf(a0, v0.z, acc0[2]);
    acc0[3] = __builtin_fmaf(a0, v0.w, acc0[3]);
    acc0[4] = __builtin_fmaf(a0, v1.x, acc0[4]);
    acc0[5] = __builtin_fmaf(a0, v1.y, acc0[5]);
    acc0[6] = __builtin_fmaf(a0, v1.z, acc0[6]);
    acc0[7] = __builtin_fmaf(a0, v1.w, acc0[7]);
    acc1[0] = __builtin_fmaf(a1, v0.x, acc1[0]);
    acc1[1] = __builtin_fmaf(a1, v0.y, acc1[1]);
    acc1[2] = __builtin_fmaf(a1, v0.z, acc1[2]);
    acc1[3] = __builtin_fmaf(a1, v0.w, acc1[3]);
    acc1[4] = __builtin_fmaf(a1, v1.x, acc1[4]);
    acc1[5] = __builtin_fmaf(a1, v1.y, acc1[5]);
    acc1[6] = __builtin_fmaf(a1, v1.z, acc1[6]);
    acc1[7] = __builtin_fmaf(a1, v1.w, acc1[7]);
  }
  float4 o;
  o = (float4){acc0[0], acc0[1], acc0[2], acc0[3]};
  *(float4*)(out + ((size_t)(b * Qn) + q0 + q2) * Dn + d0) = o;
  o = (float4){acc0[4], acc0[5], acc0[6], acc0[7]};
  *(float4*)(out + ((size_t)(b * Qn) + q0 + q2) * Dn + d0 + 4) = o;
  o = (float4){acc1[0], acc1[1], acc1[2], acc1[3]};
  *(float4*)(out + ((size_t)(b * Qn) + q0 + q2 + 1) * Dn + d0) = o;
  o = (float4){acc1[4], acc1[5], acc1[6], acc1[7]};
  *(float4*)(out + ((size_t)(b * Qn) + q0 + q2 + 1) * Dn + d0 + 4) = o;
}

extern "C" void kernel_launch(void* const* d_in, const int* in_sizes, int n_in,
                              void* d_out, int out_size, void* d_ws, size_t ws_size,
                              hipStream_t stream) {
  const float* queries    = (const float*)d_in[0];
  const float* keys       = (const float*)d_in[1];
  const float* values     = (const float*)d_in[2];
  const int*   valid_lens = (const int*)d_in[3];
  const float* Wq         = (const float*)d_in[4];
  const float* Wk         = (const float*)d_in[5];
  const float* wv         = (const float*)d_in[6];
  float* out = (float*)d_out;

  float* qp   = (float*)d_ws;                 // [2048][512]
  float* kp   = qp + 2048 * 512;              // [2048][512]
  float* attn = kp + 2048 * 512;              // [16][128][128]

  proj_kernel<<<dim3(64, 8), 256, 0, stream>>>(queries, keys, Wq, Wk, qp, kp);
  score_softmax_kernel<<<dim3(16, 16), 256, 0, stream>>>(qp, kp, wv, valid_lens, attn);
  av_kernel<<<dim3(16, 16), 256, 0, stream>>>(attn, values, out);
}

// Round 2
// 82.092 us; speedup vs baseline: 1.3846x; 1.3846x over previous
//
#include <hip/hip_runtime.h>

#define Bn 16
#define Qn 128
#define Kn 128
#define Dn 512
#define Hn 512
#define NEGV (-3.0e38f)
// 2*log2(e): projections pre-scaled so v_exp_f32 (2^x) gives e^{2(q+k)}
#define PSCALE 2.8853900817779268f

__device__ __forceinline__ float exp2_hw(float x) {
  float r;
  asm("v_exp_f32 %0, %1" : "=v"(r) : "v"(x));
  return r;
}

// ---------------- Kernel 1: projections (f32 tiled GEMM) ----------------
// Virtual C[4096][512]: rows 0..2047 = queries@Wq -> qp, rows 2048.. = keys@Wk -> kp
// Output scaled by PSCALE for the exp2-based tanh in kernel 2.
__global__ __launch_bounds__(256) void proj_kernel(
    const float* __restrict__ queries, const float* __restrict__ keys,
    const float* __restrict__ Wq, const float* __restrict__ Wk,
    float* __restrict__ qp, float* __restrict__ kp)
{
  __shared__ float AsT[16][68];
  __shared__ float Bs[16][64];
  const int t  = threadIdx.x;
  const int tx = t & 15, ty = t >> 4;
  const int rowTile = blockIdx.x;   // 0..63
  const int colTile = blockIdx.y;   // 0..7
  const bool isQ = rowTile < 32;
  const float* A = isQ ? queries : keys;
  const float* W = isQ ? Wq : Wk;
  float* C       = isQ ? qp : kp;
  const int rowBase = (isQ ? rowTile : rowTile - 32) * 64;
  const int n0 = colTile * 64;

  float c[4][4];
  #pragma unroll
  for (int i = 0; i < 4; ++i)
    #pragma unroll
    for (int j = 0; j < 4; ++j) c[i][j] = 0.f;

  const int am  = t >> 2;
  const int akq = (t & 3) * 4;
  const int bkr = t >> 4;
  const int bnq = (t & 15) * 4;

  for (int k0 = 0; k0 < Dn; k0 += 16) {
    float4 av = *(const float4*)(A + (size_t)(rowBase + am) * Dn + k0 + akq);
    float4 bv = *(const float4*)(W + (size_t)(k0 + bkr) * Hn + n0 + bnq);
    __syncthreads();
    AsT[akq + 0][am] = av.x;
    AsT[akq + 1][am] = av.y;
    AsT[akq + 2][am] = av.z;
    AsT[akq + 3][am] = av.w;
    *(float4*)&Bs[bkr][bnq] = bv;
    __syncthreads();
    #pragma unroll
    for (int kk = 0; kk < 16; ++kk) {
      float4 a4 = *(const float4*)&AsT[kk][ty * 4];
      float4 b4 = *(const float4*)&Bs[kk][tx * 4];
      float a[4] = {a4.x, a4.y, a4.z, a4.w};
      float b[4] = {b4.x, b4.y, b4.z, b4.w};
      #pragma unroll
      for (int i = 0; i < 4; ++i)
        #pragma unroll
        for (int j = 0; j < 4; ++j)
          c[i][j] = __builtin_fmaf(a[i], b[j], c[i][j]);
    }
  }
  #pragma unroll
  for (int i = 0; i < 4; ++i) {
    float4 o = {c[i][0] * PSCALE, c[i][1] * PSCALE, c[i][2] * PSCALE, c[i][3] * PSCALE};
    *(float4*)(C + (size_t)(rowBase + ty * 4 + i) * Hn + n0 + tx * 4) = o;
  }
}

// ------ Kernel 2: fused scores + masked softmax + attn@values ------
// Block = (b, 2 q-rows). 256 threads; thread owns one (q_loc, k) score.
// score' = sum_h (-2*wv[h]) * rcp(1 + exp2(qs[h]+ks[h]))   (softmax-equivalent)
__global__ __launch_bounds__(256, 4) void fused_score_av_kernel(
    const float* __restrict__ qp, const float* __restrict__ kp,
    const float* __restrict__ wv, const int* __restrict__ valid_lens,
    const float* __restrict__ values, float* __restrict__ out)
{
  __shared__ float KPl[128][65];   // stride 65: bank = (k+h)%32 -> 2-way, free
  __shared__ float QPl[2][64];
  __shared__ float WVl[512];
  __shared__ float At[2][128];
  __shared__ float Red[4];

  const int t     = threadIdx.x;
  const int b     = blockIdx.y;
  const int q0    = blockIdx.x * 2;
  const int q_loc = t >> 7;        // 0..1 (wave-uniform)
  const int kk    = t & 127;

  if (t < 128) {
    float4 w4 = *(const float4*)(wv + t * 4);
    w4.x *= -2.f; w4.y *= -2.f; w4.z *= -2.f; w4.w *= -2.f;
    *(float4*)&WVl[t * 4] = w4;
  }

  float4 kreg[8];
  float4 qreg = {0.f, 0.f, 0.f, 0.f};
  const float* kb = kp + (size_t)b * Kn * Hn;

  auto load_chunk = [&](int c) {
    #pragma unroll
    for (int it = 0; it < 8; ++it) {
      int idx = t + 256 * it;
      int r = idx >> 4, c4 = idx & 15;
      kreg[it] = *(const float4*)(kb + (size_t)r * Hn + c * 64 + c4 * 4);
    }
    if (t < 32) {
      int r = t >> 4, c4 = t & 15;
      qreg = *(const float4*)(qp + ((size_t)(b * Qn + q0 + r)) * Hn + c * 64 + c4 * 4);
    }
  };

  load_chunk(0);
  float acc = 0.f;

  for (int c = 0; c < 8; ++c) {
    __syncthreads();               // prev chunk's compute done reading LDS
    #pragma unroll
    for (int it = 0; it < 8; ++it) {
      int idx = t + 256 * it;
      int r = idx >> 4, c4 = idx & 15;
      KPl[r][c4 * 4 + 0] = kreg[it].x;
      KPl[r][c4 * 4 + 1] = kreg[it].y;
      KPl[r][c4 * 4 + 2] = kreg[it].z;
      KPl[r][c4 * 4 + 3] = kreg[it].w;
    }
    if (t < 32) {
      int r = t >> 4, c4 = t & 15;
      QPl[r][c4 * 4 + 0] = qreg.x;
      QPl[r][c4 * 4 + 1] = qreg.y;
      QPl[r][c4 * 4 + 2] = qreg.z;
      QPl[r][c4 * 4 + 3] = qreg.w;
    }
    if (c < 7) load_chunk(c + 1);  // prefetch hides under compute
    __syncthreads();

    const float* wvp = &WVl[c * 64];
    #pragma unroll
    for (int h4 = 0; h4 < 16; ++h4) {
      float4 qv = *(const float4*)&QPl[q_loc][h4 * 4];   // broadcast
      float4 w4 = *(const float4*)&wvp[h4 * 4];          // broadcast
      float k0v = KPl[kk][h4 * 4 + 0];
      float k1v = KPl[kk][h4 * 4 + 1];
      float k2v = KPl[kk][h4 * 4 + 2];
      float k3v = KPl[kk][h4 * 4 + 3];
      float r0 = __builtin_amdgcn_rcpf(1.0f + exp2_hw(qv.x + k0v));
      float r1 = __builtin_amdgcn_rcpf(1.0f + exp2_hw(qv.y + k1v));
      float r2 = __builtin_amdgcn_rcpf(1.0f + exp2_hw(qv.z + k2v));
      float r3 = __builtin_amdgcn_rcpf(1.0f + exp2_hw(qv.w + k3v));
      acc = __builtin_fmaf(w4.x, r0, acc);
      acc = __builtin_fmaf(w4.y, r1, acc);
      acc = __builtin_fmaf(w4.z, r2, acc);
      acc = __builtin_fmaf(w4.w, r3, acc);
    }
  }

  // ---- masked softmax over k (2 waves per q row) ----
  const int vlen = valid_lens[b];
  const bool ok  = kk < vlen;
  const int w    = t >> 6;
  float sv = ok ? acc : NEGV;
  #pragma unroll
  for (int xm = 32; xm >= 1; xm >>= 1) sv = fmaxf(sv, __shfl_xor(sv, xm));
  if ((t & 63) == 0) Red[w] = sv;
  __syncthreads();
  float m = fmaxf(sv, Red[w ^ 1]);

  float ev = ok ? exp2_hw((acc - m) * 1.44269504f) : 0.f;
  float s = ev;
  #pragma unroll
  for (int xm = 32; xm >= 1; xm >>= 1) s += __shfl_xor(s, xm);
  __syncthreads();                 // everyone done reading Red (max phase)
  if ((t & 63) == 0) Red[w] = s;
  __syncthreads();
  float sum = s + Red[w ^ 1];
  At[q_loc][kk] = ev * __builtin_amdgcn_rcpf(sum);
  __syncthreads();

  // ---- AV: out[b, q0+q_loc, :] = sum_k At * values[b,k,:] ----
  const int d4 = (t & 127) * 4;
  const float* vb = values + (size_t)b * Kn * Dn + d4;
  float4 o = {0.f, 0.f, 0.f, 0.f};
  #pragma unroll 8
  for (int k = 0; k < 128; ++k) {
    float a  = At[q_loc][k];       // broadcast
    float4 v = *(const float4*)(vb + (size_t)k * Dn);
    o.x = __builtin_fmaf(a, v.x, o.x);
    o.y = __builtin_fmaf(a, v.y, o.y);
    o.z = __builtin_fmaf(a, v.z, o.z);
    o.w = __builtin_fmaf(a, v.w, o.w);
  }
  *(float4*)(out + ((size_t)(b * Qn + q0 + q_loc)) * Dn + d4) = o;
}

extern "C" void kernel_launch(void* const* d_in, const int* in_sizes, int n_in,
                              void* d_out, int out_size, void* d_ws, size_t ws_size,
                              hipStream_t stream) {
  const float* queries    = (const float*)d_in[0];
  const float* keys       = (const float*)d_in[1];
  const float* values     = (const float*)d_in[2];
  const int*   valid_lens = (const int*)d_in[3];
  const float* Wq         = (const float*)d_in[4];
  const float* Wk         = (const float*)d_in[5];
  const float* wv         = (const float*)d_in[6];
  float* out = (float*)d_out;

  float* qp = (float*)d_ws;                 // [2048][512] (PSCALE-scaled)
  float* kp = qp + 2048 * 512;              // [2048][512] (PSCALE-scaled)

  proj_kernel<<<dim3(64, 8), 256, 0, stream>>>(queries, keys, Wq, Wk, qp, kp);
  fused_score_av_kernel<<<dim3(64, 16), 256, 0, stream>>>(qp, kp, wv, valid_lens,
                                                          values, out);
}

// Round 3
// 50.455 us; speedup vs baseline: 2.2529x; 1.6270x over previous
//
#include <hip/hip_runtime.h>

#define Bn 16
#define Qn 128
#define Kn 128
#define Dn 512
#define Hn 512
#define NEGV (-3.0e38f)
// 2*log2(e): exp2(PSCALE*x) == e^{2x}
#define PSCALE 2.8853900817779268f

typedef short s16x8 __attribute__((ext_vector_type(8)));
typedef float f32x4 __attribute__((ext_vector_type(4)));

__device__ __forceinline__ float exp2_hw(float x) {
  float r;
  asm("v_exp_f32 %0, %1" : "=v"(r) : "v"(x));
  return r;
}
__device__ __forceinline__ unsigned short f2bf(float f) {   // RNE f32->bf16
  unsigned int u = __float_as_uint(f);
  u += 0x7fff + ((u >> 16) & 1);
  return (unsigned short)(u >> 16);
}
__device__ __forceinline__ float bf_lo(unsigned int u) { return __uint_as_float(u << 16); }
__device__ __forceinline__ float bf_hi(unsigned int u) { return __uint_as_float(u & 0xffff0000u); }

// ---------- K1: convert inputs to bf16 (A rows, W transposed, V transposed) ----------
// blocks [0,512):   Abf[4096][512] = bf16([queries;keys])
// blocks [512,640): Wt[2][512 n][512 k] = bf16(W[k][n])   (transposed)
// blocks [640,768): Vt[16][512 d][128 k] = bf16(values[b][k][d]) (transposed)
__global__ __launch_bounds__(256) void convert_kernel(
    const float* __restrict__ queries, const float* __restrict__ keys,
    const float* __restrict__ Wq, const float* __restrict__ Wk,
    const float* __restrict__ values,
    unsigned short* __restrict__ Abf, unsigned short* __restrict__ Wt,
    unsigned short* __restrict__ Vt)
{
  const int bid = blockIdx.x, t = threadIdx.x;
  if (bid < 512) {
    const int gid = bid * 256 + t;
    const size_t base = (size_t)gid * 16;
    const float* src = (base < 1048576) ? (queries + base) : (keys + (base - 1048576));
    unsigned short o[16];
    #pragma unroll
    for (int j = 0; j < 4; ++j) {
      float4 v = *(const float4*)(src + j * 4);
      o[j * 4 + 0] = f2bf(v.x); o[j * 4 + 1] = f2bf(v.y);
      o[j * 4 + 2] = f2bf(v.z); o[j * 4 + 3] = f2bf(v.w);
    }
    #pragma unroll
    for (int j = 0; j < 4; ++j)
      *(ushort4*)(Abf + base + j * 4) = *(ushort4*)&o[j * 4];
  } else if (bid < 640) {
    const int tid = (bid - 512) * 256 + t;           // 0..32767
    const int n = tid & 511, rest = tid >> 9;        // rest 0..63
    const int sel = rest >> 5, k16 = rest & 31;
    const float* W = sel ? Wk : Wq;
    unsigned short o[16];
    #pragma unroll
    for (int i = 0; i < 16; ++i)
      o[i] = f2bf(W[(size_t)(k16 * 16 + i) * Hn + n]);
    unsigned short* dst = Wt + (size_t)sel * 262144 + (size_t)n * 512 + k16 * 16;
    #pragma unroll
    for (int j = 0; j < 4; ++j) *(ushort4*)(dst + j * 4) = *(ushort4*)&o[j * 4];
  } else {
    const int tid = (bid - 640) * 256 + t;           // 0..32767
    const int d = tid & 511, rest = tid >> 9;        // 0..63
    const int b = rest >> 2, k32 = rest & 3;
    unsigned short o[32];
    #pragma unroll
    for (int i = 0; i < 32; ++i)
      o[i] = f2bf(values[((size_t)(b * Kn + k32 * 32 + i)) * Dn + d]);
    unsigned short* dst = Vt + (size_t)b * 65536 + (size_t)d * 128 + k32 * 32;
    #pragma unroll
    for (int j = 0; j < 8; ++j) *(ushort4*)(dst + j * 4) = *(ushort4*)&o[j * 4];
  }
}

// ---------- K2: projections via bf16 MFMA; epilogue -> Eq=exp2(PSCALE*q) f32, Ek bf16 ----------
// C[4096][512]: rows<2048 q-proj -> Eq f32; rows>=2048 k-proj -> Ek bf16.
// Tiles: BM=128 BN=64 BK=64; 4 waves as 2x2 (wave tile 64x32 = 4x2 frags of 16x16).
__global__ __launch_bounds__(256) void proj_mfma(
    const unsigned short* __restrict__ Abf, const unsigned short* __restrict__ Wt,
    float* __restrict__ Eq, unsigned short* __restrict__ Ek)
{
  __shared__ unsigned short Al[128][72];   // stride 144B: 16B aligned, even banks
  __shared__ unsigned short Bl[64][72];
  const int t = threadIdx.x, w = t >> 6, l = t & 63;
  const int wm = w >> 1, wn = w & 1;
  const int rowTile = blockIdx.x;          // 0..31
  const int n0 = blockIdx.y * 64;          // col base
  const int R0 = rowTile * 128;
  const bool isQ = rowTile < 16;
  const unsigned short* Wsel = Wt + (isQ ? 0 : 262144);

  f32x4 acc[4][2];
  #pragma unroll
  for (int m = 0; m < 4; ++m)
    #pragma unroll
    for (int n = 0; n < 2; ++n) acc[m][n] = (f32x4)0.f;

  const int lr = l & 15, lk = l >> 4;      // frag row / k-group

  for (int k0 = 0; k0 < Hn; k0 += 64) {
    ushort4 ar[4][2], br[2][2];
    #pragma unroll
    for (int i = 0; i < 4; ++i) {
      int g = t + 256 * i, r = g >> 3, c = g & 7;
      const unsigned short* p = Abf + (size_t)(R0 + r) * Hn + k0 + c * 8;
      ar[i][0] = *(const ushort4*)p; ar[i][1] = *(const ushort4*)(p + 4);
    }
    #pragma unroll
    for (int i = 0; i < 2; ++i) {
      int g = t + 256 * i, r = g >> 3, c = g & 7;
      const unsigned short* p = Wsel + (size_t)(n0 + r) * Hn + k0 + c * 8;
      br[i][0] = *(const ushort4*)p; br[i][1] = *(const ushort4*)(p + 4);
    }
    __syncthreads();
    #pragma unroll
    for (int i = 0; i < 4; ++i) {
      int g = t + 256 * i, r = g >> 3, c = g & 7;
      *(ushort4*)&Al[r][c * 8] = ar[i][0]; *(ushort4*)&Al[r][c * 8 + 4] = ar[i][1];
    }
    #pragma unroll
    for (int i = 0; i < 2; ++i) {
      int g = t + 256 * i, r = g >> 3, c = g & 7;
      *(ushort4*)&Bl[r][c * 8] = br[i][0]; *(ushort4*)&Bl[r][c * 8 + 4] = br[i][1];
    }
    __syncthreads();
    #pragma unroll
    for (int ks = 0; ks < 2; ++ks) {
      s16x8 af[4], bf_[2];
      #pragma unroll
      for (int m = 0; m < 4; ++m)
        af[m] = *(const s16x8*)&Al[wm * 64 + m * 16 + lr][ks * 32 + lk * 8];
      #pragma unroll
      for (int n = 0; n < 2; ++n)
        bf_[n] = *(const s16x8*)&Bl[wn * 32 + n * 16 + lr][ks * 32 + lk * 8];
      #pragma unroll
      for (int m = 0; m < 4; ++m)
        #pragma unroll
        for (int n = 0; n < 2; ++n)
          acc[m][n] = __builtin_amdgcn_mfma_f32_16x16x32_bf16(af[m], bf_[n], acc[m][n], 0, 0, 0);
    }
    __syncthreads();
  }

  #pragma unroll
  for (int m = 0; m < 4; ++m)
    #pragma unroll
    for (int n = 0; n < 2; ++n)
      #pragma unroll
      for (int r = 0; r < 4; ++r) {
        int row = R0 + wm * 64 + m * 16 + lk * 4 + r;
        int col = n0 + wn * 32 + n * 16 + lr;
        float e = exp2_hw(acc[m][n][r] * PSCALE);
        if (isQ) Eq[(size_t)row * Hn + col] = e;
        else     Ek[(size_t)(row - 2048) * Hn + col] = f2bf(e);
      }
}

// ---------- K3: scores via factored exp + masked softmax -> At bf16 ----------
// Block=(2 q-rows, b). score' = sum_h wvs[h]/(1+Eq*Ek), wvs=-2wv. Paired rcp.
__global__ __launch_bounds__(256) void score_kernel(
    const float* __restrict__ Eq, const unsigned short* __restrict__ Ek,
    const float* __restrict__ wv, const int* __restrict__ valid_lens,
    unsigned short* __restrict__ At)
{
  __shared__ unsigned short EkL[128][68];  // stride 136B: b64-aligned, conflict-free
  __shared__ float EqL[2][72];
  __shared__ float WVL[512];
  __shared__ float Red[4];

  const int t = threadIdx.x;
  const int b = blockIdx.y;
  const int q0 = blockIdx.x * 2;
  const int q_loc = t >> 7, kk = t & 127;

  if (t < 128) {
    float4 w4 = *(const float4*)(wv + t * 4);
    w4.x *= -2.f; w4.y *= -2.f; w4.z *= -2.f; w4.w *= -2.f;
    *(float4*)&WVL[t * 4] = w4;
  }

  uint2 ekr[8];
  float4 eqr = {0.f, 0.f, 0.f, 0.f};
  const unsigned short* Ekb = Ek + (size_t)b * Kn * Hn;

  auto prefetch = [&](int c) {
    #pragma unroll
    for (int i = 0; i < 8; ++i) {
      int g = t + 256 * i, r = g >> 4, c4 = g & 15;
      ekr[i] = *(const uint2*)(Ekb + (size_t)r * Hn + c * 64 + c4 * 4);
    }
    if (t < 32) {
      int r = t >> 4, c4 = t & 15;
      eqr = *(const float4*)(Eq + ((size_t)(b * Qn + q0 + r)) * Hn + c * 64 + c4 * 4);
    }
  };

  prefetch(0);
  float acc = 0.f;

  for (int c = 0; c < 8; ++c) {
    __syncthreads();
    #pragma unroll
    for (int i = 0; i < 8; ++i) {
      int g = t + 256 * i, r = g >> 4, c4 = g & 15;
      *(uint2*)&EkL[r][c4 * 4] = ekr[i];
    }
    if (t < 32) {
      int r = t >> 4, c4 = t & 15;
      *(float4*)&EqL[r][c4 * 4] = eqr;
    }
    if (c < 7) prefetch(c + 1);
    __syncthreads();

    #pragma unroll
    for (int h8 = 0; h8 < 8; ++h8) {
      uint2 e0 = *(const uint2*)&EkL[kk][h8 * 8];
      uint2 e1 = *(const uint2*)&EkL[kk][h8 * 8 + 4];
      float4 qa = *(const float4*)&EqL[q_loc][h8 * 8];
      float4 qb = *(const float4*)&EqL[q_loc][h8 * 8 + 4];
      float4 wa = *(const float4*)&WVL[c * 64 + h8 * 8];
      float4 wb = *(const float4*)&WVL[c * 64 + h8 * 8 + 4];
      float A, B, num, den;
      A = __builtin_fmaf(qa.x, bf_lo(e0.x), 1.f);
      B = __builtin_fmaf(qa.y, bf_hi(e0.x), 1.f);
      num = __builtin_fmaf(wa.y, A, wa.x * B);
      den = A * B;
      acc = __builtin_fmaf(num, __builtin_amdgcn_rcpf(den), acc);
      A = __builtin_fmaf(qa.z, bf_lo(e0.y), 1.f);
      B = __builtin_fmaf(qa.w, bf_hi(e0.y), 1.f);
      num = __builtin_fmaf(wa.w, A, wa.z * B);
      den = A * B;
      acc = __builtin_fmaf(num, __builtin_amdgcn_rcpf(den), acc);
      A = __builtin_fmaf(qb.x, bf_lo(e1.x), 1.f);
      B = __builtin_fmaf(qb.y, bf_hi(e1.x), 1.f);
      num = __builtin_fmaf(wb.y, A, wb.x * B);
      den = A * B;
      acc = __builtin_fmaf(num, __builtin_amdgcn_rcpf(den), acc);
      A = __builtin_fmaf(qb.z, bf_lo(e1.y), 1.f);
      B = __builtin_fmaf(qb.w, bf_hi(e1.y), 1.f);
      num = __builtin_fmaf(wb.w, A, wb.z * B);
      den = A * B;
      acc = __builtin_fmaf(num, __builtin_amdgcn_rcpf(den), acc);
    }
  }

  // masked softmax over k (2 waves per q row)
  const int vlen = valid_lens[b];
  const bool ok = kk < vlen;
  const int w = t >> 6;
  float sv = ok ? acc : NEGV;
  #pragma unroll
  for (int xm = 32; xm >= 1; xm >>= 1) sv = fmaxf(sv, __shfl_xor(sv, xm));
  if ((t & 63) == 0) Red[w] = sv;
  __syncthreads();
  float m = fmaxf(sv, Red[w ^ 1]);
  float ev = ok ? exp2_hw((acc - m) * 1.44269504f) : 0.f;
  float s = ev;
  #pragma unroll
  for (int xm = 32; xm >= 1; xm >>= 1) s += __shfl_xor(s, xm);
  __syncthreads();
  if ((t & 63) == 0) Red[w] = s;
  __syncthreads();
  float sum = s + Red[w ^ 1];
  At[((size_t)(b * Qn) + q0 + q_loc) * Kn + kk] = f2bf(ev * __builtin_amdgcn_rcpf(sum));
}

// ---------- K4: out = At @ V via bf16 MFMA ----------
// Per (b, d-tile 128). BM=128(q) BN=128(d) K=128 in 2 halves. 4 waves 2x2, 4x4 frags.
__global__ __launch_bounds__(256) void av_mfma(
    const unsigned short* __restrict__ At, const unsigned short* __restrict__ Vt,
    float* __restrict__ out)
{
  __shared__ unsigned short AtL[128][72];
  __shared__ unsigned short VL[128][72];
  const int t = threadIdx.x, w = t >> 6, l = t & 63;
  const int wm = w >> 1, wn = w & 1;
  const int dt = blockIdx.x;               // 0..3
  const int b = blockIdx.y;
  const int lr = l & 15, lk = l >> 4;

  f32x4 acc[4][4];
  #pragma unroll
  for (int m = 0; m < 4; ++m)
    #pragma unroll
    for (int n = 0; n < 4; ++n) acc[m][n] = (f32x4)0.f;

  const unsigned short* Atb = At + (size_t)b * Qn * Kn;
  const unsigned short* Vtb = Vt + (size_t)b * 65536 + (size_t)dt * 128 * Kn;

  for (int k0 = 0; k0 < Kn; k0 += 64) {
    ushort4 ar[4][2], vr[4][2];
    #pragma unroll
    for (int i = 0; i < 4; ++i) {
      int g = t + 256 * i, r = g >> 3, c = g & 7;
      const unsigned short* p = Atb + (size_t)r * Kn + k0 + c * 8;
      ar[i][0] = *(const ushort4*)p; ar[i][1] = *(const ushort4*)(p + 4);
      const unsigned short* pv = Vtb + (size_t)r * Kn + k0 + c * 8;
      vr[i][0] = *(const ushort4*)pv; vr[i][1] = *(const ushort4*)(pv + 4);
    }
    __syncthreads();
    #pragma unroll
    for (int i = 0; i < 4; ++i) {
      int g = t + 256 * i, r = g >> 3, c = g & 7;
      *(ushort4*)&AtL[r][c * 8] = ar[i][0]; *(ushort4*)&AtL[r][c * 8 + 4] = ar[i][1];
      *(ushort4*)&VL[r][c * 8] = vr[i][0];  *(ushort4*)&VL[r][c * 8 + 4] = vr[i][1];
    }
    __syncthreads();
    #pragma unroll
    for (int ks = 0; ks < 2; ++ks) {
      s16x8 af[4], bf_[4];
      #pragma unroll
      for (int m = 0; m < 4; ++m)
        af[m] = *(const s16x8*)&AtL[wm * 64 + m * 16 + lr][ks * 32 + lk * 8];
      #pragma unroll
      for (int n = 0; n < 4; ++n)
        bf_[n] = *(const s16x8*)&VL[wn * 64 + n * 16 + lr][ks * 32 + lk * 8];
      #pragma unroll
      for (int m = 0; m < 4; ++m)
        #pragma unroll
        for (int n = 0; n < 4; ++n)
          acc[m][n] = __builtin_amdgcn_mfma_f32_16x16x32_bf16(af[m], bf_[n], acc[m][n], 0, 0, 0);
    }
    __syncthreads();
  }

  #pragma unroll
  for (int m = 0; m < 4; ++m)
    #pragma unroll
    for (int n = 0; n < 4; ++n)
      #pragma unroll
      for (int r = 0; r < 4; ++r) {
        int row = wm * 64 + m * 16 + lk * 4 + r;
        int col = dt * 128 + wn * 64 + n * 16 + lr;
        out[((size_t)(b * Qn) + row) * Dn + col] = acc[m][n][r];
      }
}

extern "C" void kernel_launch(void* const* d_in, const int* in_sizes, int n_in,
                              void* d_out, int out_size, void* d_ws, size_t ws_size,
                              hipStream_t stream) {
  const float* queries    = (const float*)d_in[0];
  const float* keys       = (const float*)d_in[1];
  const float* values     = (const float*)d_in[2];
  const int*   valid_lens = (const int*)d_in[3];
  const float* Wq         = (const float*)d_in[4];
  const float* Wk         = (const float*)d_in[5];
  const float* wv         = (const float*)d_in[6];
  float* out = (float*)d_out;

  unsigned short* Abf = (unsigned short*)d_ws;     // 4096*512 bf16      (4MB)
  unsigned short* Wt  = Abf + 2097152;             // 2*512*512 bf16     (1MB)
  unsigned short* Vt  = Wt + 524288;               // 16*512*128 bf16    (2MB)
  float*          Eq  = (float*)(Vt + 1048576);    // 2048*512 f32       (4MB)
  unsigned short* Ek  = (unsigned short*)(Eq + 1048576); // 2048*512 bf16 (2MB)
  unsigned short* At  = Ek + 1048576;              // 16*128*128 bf16    (0.5MB)

  convert_kernel<<<768, 256, 0, stream>>>(queries, keys, Wq, Wk, values, Abf, Wt, Vt);
  proj_mfma<<<dim3(32, 8), 256, 0, stream>>>(Abf, Wt, Eq, Ek);
  score_kernel<<<dim3(64, 16), 256, 0, stream>>>(Eq, Ek, wv, valid_lens, At);
  av_mfma<<<dim3(4, 16), 256, 0, stream>>>(At, Vt, out);
}